// Round 1
// baseline (208.935 us; speedup 1.0000x reference)
//
#include <hip/hip_runtime.h>
#include <hip/hip_bf16.h>
#include <math.h>

// MHCLayerAITERFused: B=8192, N=4, C=4096, fp32 in/out.
// out[b,n,c] = sum_m M[n,m]*x[b,m,c] + hpost[n]*bf16(rmsnorm(sum_m hpre[m]*x[b,m,c])*w[c])
// Memory-bound: 512MB read + 512MB write -> ~170us floor at 6.3TB/s.

constexpr float kEPS = 1e-6f;

// ---- prep: sigmoid(H_pre), 2*sigmoid(H_post), sinkhorn(exp(H_res)) -> ws[24]
__global__ void mhc_prep(const float* __restrict__ H_pre,
                         const float* __restrict__ H_post,
                         const float* __restrict__ H_res,
                         float* __restrict__ ws) {
  if (threadIdx.x != 0 || blockIdx.x != 0) return;
  float P[4][4];
  #pragma unroll
  for (int i = 0; i < 4; ++i)
    #pragma unroll
    for (int j = 0; j < 4; ++j)
      P[i][j] = expf(H_res[i * 4 + j]);
  for (int it = 0; it < 3; ++it) {
    #pragma unroll
    for (int i = 0; i < 4; ++i) {
      float s = P[i][0] + P[i][1] + P[i][2] + P[i][3] + kEPS;
      float r = 1.0f / s;
      #pragma unroll
      for (int j = 0; j < 4; ++j) P[i][j] *= r;
    }
    #pragma unroll
    for (int j = 0; j < 4; ++j) {
      float s = P[0][j] + P[1][j] + P[2][j] + P[3][j] + kEPS;
      float r = 1.0f / s;
      #pragma unroll
      for (int i = 0; i < 4; ++i) P[i][j] *= r;
    }
  }
  #pragma unroll
  for (int n = 0; n < 4; ++n) ws[n] = 1.0f / (1.0f + expf(-H_pre[n]));
  #pragma unroll
  for (int n = 0; n < 4; ++n) ws[4 + n] = 2.0f / (1.0f + expf(-H_post[n]));
  #pragma unroll
  for (int i = 0; i < 4; ++i)
    #pragma unroll
    for (int j = 0; j < 4; ++j)
      ws[8 + i * 4 + j] = P[i][j];
}

__device__ __forceinline__ float uni(float v) {
  return __int_as_float(__builtin_amdgcn_readfirstlane(__float_as_int(v)));
}

// round-to-nearest-even fp32 -> bf16 -> fp32 (matches astype(bfloat16))
__device__ __forceinline__ float bf16_round(float v) {
  unsigned u = __float_as_uint(v);
  u = (u + 0x7fffu + ((u >> 16) & 1u)) & 0xffff0000u;
  return __uint_as_float(u);
}

// one block per batch row; 256 threads; each thread: 4 float4 chunks per stream
__global__ __launch_bounds__(256) void mhc_main(
    const float4* __restrict__ x4,
    const float4* __restrict__ w4,
    const float* __restrict__ ws,
    float4* __restrict__ out4) {
  const int b = blockIdx.x;
  const int tid = threadIdx.x;

  // uniform constants -> SGPRs
  float hpre[4], hpost[4], M[4][4];
  #pragma unroll
  for (int n = 0; n < 4; ++n) hpre[n] = uni(ws[n]);
  #pragma unroll
  for (int n = 0; n < 4; ++n) hpost[n] = uni(ws[4 + n]);
  #pragma unroll
  for (int i = 0; i < 4; ++i)
    #pragma unroll
    for (int j = 0; j < 4; ++j)
      M[i][j] = uni(ws[8 + i * 4 + j]);

  const size_t rowBase = (size_t)b * 4096;  // float4 units: 4 streams * 1024

  // load x[b,:,:] into registers, fully coalesced (lane-consecutive float4s)
  float xv[4][16];
  #pragma unroll
  for (int n = 0; n < 4; ++n) {
    #pragma unroll
    for (int k = 0; k < 4; ++k) {
      float4 t = x4[rowBase + n * 1024 + k * 256 + tid];
      xv[n][k * 4 + 0] = t.x; xv[n][k * 4 + 1] = t.y;
      xv[n][k * 4 + 2] = t.z; xv[n][k * 4 + 3] = t.w;
    }
  }

  // weighted aggregation over streams
  float agg[16];
  #pragma unroll
  for (int j = 0; j < 16; ++j)
    agg[j] = hpre[0] * xv[0][j] + hpre[1] * xv[1][j] +
             hpre[2] * xv[2][j] + hpre[3] * xv[3][j];

  // sum of squares over the row (4096 elems)
  float ssq = 0.0f;
  #pragma unroll
  for (int j = 0; j < 16; ++j) ssq += agg[j] * agg[j];
  #pragma unroll
  for (int off = 32; off > 0; off >>= 1) ssq += __shfl_xor(ssq, off, 64);

  __shared__ float sred[4];
  const int wave = tid >> 6;
  const int lane = tid & 63;
  if (lane == 0) sred[wave] = ssq;
  __syncthreads();
  const float total = sred[0] + sred[1] + sred[2] + sred[3];
  const float inv = 1.0f / sqrtf(total * (1.0f / 4096.0f) + kEPS);

  // y_norm with bf16 round-trip
  float yn[16];
  #pragma unroll
  for (int k = 0; k < 4; ++k) {
    float4 t = w4[k * 256 + tid];
    yn[k * 4 + 0] = bf16_round(agg[k * 4 + 0] * inv * t.x);
    yn[k * 4 + 1] = bf16_round(agg[k * 4 + 1] * inv * t.y);
    yn[k * 4 + 2] = bf16_round(agg[k * 4 + 2] * inv * t.z);
    yn[k * 4 + 3] = bf16_round(agg[k * 4 + 3] * inv * t.w);
  }

  // mixed + hpost*y_norm, write out
  #pragma unroll
  for (int n = 0; n < 4; ++n) {
    #pragma unroll
    for (int k = 0; k < 4; ++k) {
      float4 o;
      #pragma unroll
      for (int c = 0; c < 4; ++c) {
        const int j = k * 4 + c;
        float v = M[n][0] * xv[0][j] + M[n][1] * xv[1][j] +
                  M[n][2] * xv[2][j] + M[n][3] * xv[3][j] +
                  hpost[n] * yn[j];
        (&o.x)[c] = v;
      }
      out4[rowBase + n * 1024 + k * 256 + tid] = o;
    }
  }
}

extern "C" void kernel_launch(void* const* d_in, const int* in_sizes, int n_in,
                              void* d_out, int out_size, void* d_ws, size_t ws_size,
                              hipStream_t stream) {
  const float* x      = (const float*)d_in[0];
  const float* w      = (const float*)d_in[1];
  const float* H_pre  = (const float*)d_in[2];
  const float* H_post = (const float*)d_in[3];
  const float* H_res  = (const float*)d_in[4];
  float* out = (float*)d_out;
  float* ws  = (float*)d_ws;

  mhc_prep<<<1, 64, 0, stream>>>(H_pre, H_post, H_res, ws);
  mhc_main<<<8192, 256, 0, stream>>>((const float4*)x, (const float4*)w, ws,
                                     (float4*)out);
}

// Round 3
// 180.598 us; speedup vs baseline: 1.1569x; 1.1569x over previous
//
#include <hip/hip_runtime.h>
#include <hip/hip_bf16.h>
#include <math.h>

// MHCLayerAITERFused: B=8192, N=4, C=4096, fp32 in/out.
// out[b,n,c] = sum_m M[n,m]*x[b,m,c] + hpost[n]*bf16(rmsnorm(sum_m hpre[m]*x[b,m,c])*w[c])
// Memory-bound: 512MB read + 512MB write -> ~170us floor at ~6.3-6.8 TB/s.
// R3: same as R2 but with native ext_vector float4 so nontemporal builtins compile.

constexpr float kEPS = 1e-6f;

typedef float f32x4 __attribute__((ext_vector_type(4)));

// ---- prep: sigmoid(H_pre), 2*sigmoid(H_post), sinkhorn(exp(H_res)) -> ws[24]
__global__ void mhc_prep(const float* __restrict__ H_pre,
                         const float* __restrict__ H_post,
                         const float* __restrict__ H_res,
                         float* __restrict__ ws) {
  if (threadIdx.x != 0 || blockIdx.x != 0) return;
  float P[4][4];
  #pragma unroll
  for (int i = 0; i < 4; ++i)
    #pragma unroll
    for (int j = 0; j < 4; ++j)
      P[i][j] = expf(H_res[i * 4 + j]);
  for (int it = 0; it < 3; ++it) {
    #pragma unroll
    for (int i = 0; i < 4; ++i) {
      float s = P[i][0] + P[i][1] + P[i][2] + P[i][3] + kEPS;
      float r = 1.0f / s;
      #pragma unroll
      for (int j = 0; j < 4; ++j) P[i][j] *= r;
    }
    #pragma unroll
    for (int j = 0; j < 4; ++j) {
      float s = P[0][j] + P[1][j] + P[2][j] + P[3][j] + kEPS;
      float r = 1.0f / s;
      #pragma unroll
      for (int i = 0; i < 4; ++i) P[i][j] *= r;
    }
  }
  #pragma unroll
  for (int n = 0; n < 4; ++n) ws[n] = 1.0f / (1.0f + expf(-H_pre[n]));
  #pragma unroll
  for (int n = 0; n < 4; ++n) ws[4 + n] = 2.0f / (1.0f + expf(-H_post[n]));
  #pragma unroll
  for (int i = 0; i < 4; ++i)
    #pragma unroll
    for (int j = 0; j < 4; ++j)
      ws[8 + i * 4 + j] = P[i][j];
}

__device__ __forceinline__ float uni(float v) {
  return __int_as_float(__builtin_amdgcn_readfirstlane(__float_as_int(v)));
}

// round-to-nearest-even fp32 -> bf16 -> fp32 (matches astype(bfloat16))
__device__ __forceinline__ float bf16_round(float v) {
  unsigned u = __float_as_uint(v);
  u = (u + 0x7fffu + ((u >> 16) & 1u)) & 0xffff0000u;
  return __uint_as_float(u);
}

// one block per batch row; 1024 threads; each thread: one float4 per stream
__global__ __launch_bounds__(1024) void mhc_main(
    const f32x4* __restrict__ x4,
    const f32x4* __restrict__ w4,
    const float* __restrict__ ws,
    f32x4* __restrict__ out4) {
  const int b = blockIdx.x;
  const int tid = threadIdx.x;
  const size_t rowBase = (size_t)b * 4096;  // f32x4 units: 4 streams * 1024

  // issue all global loads up front: 4 x-chunks (non-temporal) + w chunk
  f32x4 xv[4];
  #pragma unroll
  for (int n = 0; n < 4; ++n)
    xv[n] = __builtin_nontemporal_load(&x4[rowBase + n * 1024 + tid]);
  const f32x4 wv = w4[tid];

  // uniform constants -> SGPRs (independent scalar loads, overlap with above)
  float hpre[4], hpost[4], M[4][4];
  #pragma unroll
  for (int n = 0; n < 4; ++n) hpre[n] = uni(ws[n]);
  #pragma unroll
  for (int n = 0; n < 4; ++n) hpost[n] = uni(ws[4 + n]);
  #pragma unroll
  for (int i = 0; i < 4; ++i)
    #pragma unroll
    for (int j = 0; j < 4; ++j)
      M[i][j] = uni(ws[8 + i * 4 + j]);

  // weighted aggregation over streams
  f32x4 agg = hpre[0] * xv[0] + hpre[1] * xv[1] + hpre[2] * xv[2] + hpre[3] * xv[3];

  // sum of squares over the row (4096 elems): wave shfl + 16-wave LDS reduce
  float ssq = agg.x * agg.x + agg.y * agg.y + agg.z * agg.z + agg.w * agg.w;
  #pragma unroll
  for (int off = 32; off > 0; off >>= 1) ssq += __shfl_xor(ssq, off, 64);

  __shared__ float sred[16];
  const int wave = tid >> 6;
  const int lane = tid & 63;
  if (lane == 0) sred[wave] = ssq;
  __syncthreads();
  float total = 0.0f;
  #pragma unroll
  for (int i = 0; i < 16; ++i) total += sred[i];
  const float inv = 1.0f / sqrtf(total * (1.0f / 4096.0f) + kEPS);

  // y_norm with bf16 round-trip
  f32x4 yn;
  #pragma unroll
  for (int c = 0; c < 4; ++c)
    yn[c] = bf16_round(agg[c] * inv * wv[c]);

  // mixed + hpost*y_norm, non-temporal write
  #pragma unroll
  for (int n = 0; n < 4; ++n) {
    f32x4 o = M[n][0] * xv[0] + M[n][1] * xv[1] + M[n][2] * xv[2] +
              M[n][3] * xv[3] + hpost[n] * yn;
    __builtin_nontemporal_store(o, &out4[rowBase + n * 1024 + tid]);
  }
}

extern "C" void kernel_launch(void* const* d_in, const int* in_sizes, int n_in,
                              void* d_out, int out_size, void* d_ws, size_t ws_size,
                              hipStream_t stream) {
  const float* x      = (const float*)d_in[0];
  const float* w      = (const float*)d_in[1];
  const float* H_pre  = (const float*)d_in[2];
  const float* H_post = (const float*)d_in[3];
  const float* H_res  = (const float*)d_in[4];
  float* out = (float*)d_out;
  float* ws  = (float*)d_ws;

  mhc_prep<<<1, 64, 0, stream>>>(H_pre, H_post, H_res, ws);
  mhc_main<<<8192, 1024, 0, stream>>>((const f32x4*)x, (const f32x4*)w, ws,
                                      (f32x4*)out);
}